// Round 9
// baseline (464.674 us; speedup 1.0000x reference)
//
#include <hip/hip_runtime.h>

#define HID 52
#define HID2 104
#define P1_CHUNK 8192
#define NBIN_MAX 512      // bins of 256 nodes; N <= 131072
#define HSTRIDE 136

typedef unsigned short ushort_t;
typedef unsigned int uint_t;
typedef short bf16x8 __attribute__((ext_vector_type(8)));
typedef float f32x4 __attribute__((ext_vector_type(4)));
typedef float f32x2 __attribute__((ext_vector_type(2)));

__device__ __forceinline__ ushort_t f2bf(float f) {
    union { float f; uint_t u; } c; c.f = f;
    uint_t u = c.u + 0x7FFFu + ((c.u >> 16) & 1u);   // RNE
    return (ushort_t)(u >> 16);
}
__device__ __forceinline__ float bflo(uint_t u) {
    union { uint_t u; float f; } c; c.u = u << 16; return c.f;
}
__device__ __forceinline__ float bfhi(uint_t u) {
    union { uint_t u; float f; } c; c.u = u & 0xFFFF0000u; return c.f;
}
__device__ __forceinline__ f32x2 unpk(uint_t u) {
    return (f32x2){bflo(u), bfhi(u)};
}

// ---------- two-pass dst-radix CSR build (unchanged R8) ----------

__global__ __launch_bounds__(256) void bhist_kernel(const int* __restrict__ dst,
                                                    int* __restrict__ ghist, int E) {
    __shared__ int lh[NBIN_MAX];
    int tid = threadIdx.x;
    lh[tid] = 0; lh[tid + 256] = 0;
    __syncthreads();
    int base = blockIdx.x * P1_CHUNK;
    int cend = min(P1_CHUNK, E - base);
    for (int i = tid; i < cend; i += 256) atomicAdd(&lh[dst[base + i] >> 8], 1);
    __syncthreads();
    int c = lh[tid];       if (c) atomicAdd(&ghist[tid], c);
    c = lh[tid + 256];     if (c) atomicAdd(&ghist[tid + 256], c);
}

__global__ __launch_bounds__(256) void bscan_kernel(const int* __restrict__ ghist,
                                                    int* __restrict__ binstart,
                                                    int* __restrict__ gcur,
                                                    int NBIN, int E) {
    __shared__ int c[NBIN_MAX];
    __shared__ int ps[256];
    int tid = threadIdx.x;
    int b0 = 2 * tid, b1 = 2 * tid + 1;
    c[b0] = ghist[b0]; c[b1] = ghist[b1];
    __syncthreads();
    int pair = c[b0] + c[b1];
    ps[tid] = pair;
    __syncthreads();
    for (int off = 1; off < 256; off <<= 1) {
        int t = (tid >= off) ? ps[tid - off] : 0;
        __syncthreads();
        ps[tid] += t;
        __syncthreads();
    }
    int ex = ps[tid] - pair;
    binstart[b0] = ex;        gcur[b0] = ex;
    binstart[b1] = ex + c[b0]; gcur[b1] = ex + c[b0];
    if (tid == 0) binstart[NBIN] = E;
}

__global__ __launch_bounds__(256) void pass1_kernel(const int* __restrict__ src,
                                                    const int* __restrict__ dst,
                                                    int* __restrict__ gcur,
                                                    uint_t* __restrict__ packed, int E) {
    __shared__ uint_t stage[P1_CHUNK];
    __shared__ ushort_t sbin[P1_CHUNK];
    __shared__ int cnt[NBIN_MAX];
    __shared__ int sst[NBIN_MAX];
    __shared__ int curs[NBIN_MAX];
    __shared__ int gbase[NBIN_MAX];
    __shared__ int ps[256];
    int tid = threadIdx.x;
    int base = blockIdx.x * P1_CHUNK;
    int cend = min(P1_CHUNK, E - base);
    cnt[tid] = 0; cnt[tid + 256] = 0;
    __syncthreads();
    for (int i = tid; i < cend; i += 256) atomicAdd(&cnt[dst[base + i] >> 8], 1);
    __syncthreads();
    int b0 = 2 * tid, b1 = 2 * tid + 1;
    int c0 = cnt[b0], c1 = cnt[b1];
    int pair = c0 + c1;
    ps[tid] = pair;
    __syncthreads();
    for (int off = 1; off < 256; off <<= 1) {
        int t = (tid >= off) ? ps[tid - off] : 0;
        __syncthreads();
        ps[tid] += t;
        __syncthreads();
    }
    int ex = ps[tid] - pair;
    sst[b0] = ex;       curs[b0] = ex;
    sst[b1] = ex + c0;  curs[b1] = ex + c0;
    gbase[b0] = c0 ? atomicAdd(&gcur[b0], c0) : 0;
    gbase[b1] = c1 ? atomicAdd(&gcur[b1], c1) : 0;
    __syncthreads();
    for (int i = tid; i < cend; i += 256) {
        int d = dst[base + i];
        int s = src[base + i];
        int b = d >> 8;
        int pos = atomicAdd(&curs[b], 1);
        stage[pos] = ((uint_t)s << 8) | (uint_t)(d & 255);
        sbin[pos] = (ushort_t)b;
    }
    __syncthreads();
    for (int i = tid; i < cend; i += 256) {
        int b = sbin[i];
        packed[gbase[b] + (i - sst[b])] = stage[i];
    }
}

__global__ __launch_bounds__(256) void pass2_kernel(const uint_t* __restrict__ packed,
                                                    const int* __restrict__ binstart,
                                                    int* __restrict__ srcsorted,
                                                    int* __restrict__ nrs,
                                                    int* __restrict__ ndeg, int N) {
    __shared__ int ncnt[256];
    __shared__ int ps[256];
    __shared__ int curs[256];
    int b = blockIdx.x;
    int beg = binstart[b], end = binstart[b + 1];
    int obase = beg + b * 4096;
    int tid = threadIdx.x;
    ncnt[tid] = 0;
    __syncthreads();
    for (int i = beg + tid; i < end; i += 256) atomicAdd(&ncnt[packed[i] & 255u], 1);
    __syncthreads();
    int v = ncnt[tid];
    int pv = (v + 15) & ~15;
    ps[tid] = pv;
    __syncthreads();
    for (int off = 1; off < 256; off <<= 1) {
        int t = (tid >= off) ? ps[tid - off] : 0;
        __syncthreads();
        ps[tid] += t;
        __syncthreads();
    }
    int start = obase + ps[tid] - pv;
    int node = b * 256 + tid;
    if (node < N) { nrs[node] = start; ndeg[node] = pv; }
    curs[tid] = start;
    __syncthreads();
    for (int i = beg + tid; i < end; i += 256) {
        uint_t p = packed[i];
        int pos = atomicAdd(&curs[p & 255u], 1);
        srcsorted[pos] = (int)(p >> 8);
    }
    __syncthreads();
    for (int i = start + v; i < start + pv; i++) srcsorted[i] = N;   // zero-row pads
}

// ---------- fused setup: conv_x + zero pad rows + conv_w + zero ghist ----------
__global__ __launch_bounds__(256) void setup_kernel(const float* __restrict__ x,
                                                    const float* __restrict__ w1,
                                                    const float* __restrict__ w2,
                                                    const float* __restrict__ lin_w,
                                                    ushort_t* __restrict__ xb,
                                                    ushort_t* __restrict__ h1b,
                                                    ushort_t* __restrict__ h2b,
                                                    ushort_t* __restrict__ w1f,
                                                    ushort_t* __restrict__ w2f,
                                                    ushort_t* __restrict__ linf,
                                                    int* __restrict__ ghist,
                                                    int n, int nxblk) {
    int blk = blockIdx.x;
    int tid = threadIdx.x;
    if (blk < nxblk) {
        int t = blk * 256 + tid;
        if (t >= n * 16) return;
        int node = t >> 4, pp = t & 15;
        int c0 = pp * 4;
        ushort_t o[4];
#pragma unroll
        for (int j = 0; j < 4; j++) {
            int c = c0 + j;
            o[j] = (c < HID) ? f2bf(x[(size_t)node * HID + c]) : 0;
        }
        uint_t u0 = (uint_t)o[0] | ((uint_t)o[1] << 16);
        uint_t u1 = (uint_t)o[2] | ((uint_t)o[3] << 16);
        *(uint2*)(xb + (size_t)node * 64 + c0) = make_uint2(u0, u1);
        return;
    }
    if (blk == nxblk) {
        ushort_t* arr = (tid < 64) ? xb : (tid < 128) ? h1b : h2b;
        arr[(size_t)n * 64 + (tid & 63)] = 0;    // threads 192..255 dup-write h2b: benign
        ghist[tid] = 0; ghist[tid + 256] = 0;
        return;
    }
    int gid = (blk - nxblk - 1) * 4 + (tid >> 6);
    int lane = tid & 63;
    if (gid >= 122) return;
    int m = lane & 15, q = lane >> 4;
    ushort_t o[8];
    ushort_t* dstp;
    if (gid < 42) {
        int l = gid / 14, r = gid % 14, ct = r >> 1, ks = r & 1;
        int nn = ct * 16 + m;
#pragma unroll
        for (int j = 0; j < 8; j++) {
            int k = ks * 32 + q * 8 + j;
            o[j] = (k < HID && nn < HID2) ? f2bf(w1[((size_t)l * HID + k) * HID2 + nn]) : 0;
        }
        dstp = w1f + ((size_t)(l * 14 + ct * 2 + ks) * 64 + lane) * 8;
    } else if (gid < 90) {
        int g2 = gid - 42, l = g2 / 16, r = g2 % 16, ct = r >> 2, ks = r & 3;
        int nn = ct * 16 + m;
#pragma unroll
        for (int j = 0; j < 8; j++) {
            int k = ks * 32 + q * 8 + j;
            o[j] = (k < HID2 && nn < HID) ? f2bf(w2[((size_t)l * HID2 + k) * HID + nn]) : 0;
        }
        dstp = w2f + ((size_t)(l * 16 + ct * 4 + ks) * 64 + lane) * 8;
    } else {
        int g2 = gid - 90, ct = g2 >> 3, ks = g2 & 7;
        int nn = ct * 16 + m;
#pragma unroll
        for (int j = 0; j < 8; j++) {
            int kg = ks * 32 + q * 8 + j;
            int seg = kg >> 6, kk = kg & 63;
            o[j] = (kk < HID && nn < HID) ? f2bf(lin_w[((size_t)seg * HID + kk) * HID + nn]) : 0;
        }
        dstp = linf + ((size_t)(ct * 8 + ks) * 64 + lane) * 8;
    }
    uint4 u;
    u.x = (uint_t)o[0] | ((uint_t)o[1] << 16);
    u.y = (uint_t)o[2] | ((uint_t)o[3] << 16);
    u.z = (uint_t)o[4] | ((uint_t)o[5] << 16);
    u.w = (uint_t)o[6] | ((uint_t)o[7] << 16);
    *(uint4*)dstp = u;
}

// ---------- fused layer: agg (wave x 16 nodes -> LDS z tile) + MFMA MLP;
// LAST=1 additionally fuses the final concat linear (h3 never hits global) ----------
template<int LAST>
__global__ __launch_bounds__(256) void layer_kernel(
        const ushort_t* __restrict__ hbin,
        const int* __restrict__ nrs, const int* __restrict__ ndeg,
        const int* __restrict__ srcsorted,
        const float* __restrict__ eps,
        const ushort_t* __restrict__ w1f, const float* __restrict__ b1,
        const ushort_t* __restrict__ w2f, const float* __restrict__ b2,
        ushort_t* __restrict__ hbout,
        const ushort_t* __restrict__ xb, const ushort_t* __restrict__ h1b,
        const ushort_t* __restrict__ linf, const float* __restrict__ lin_b,
        float* __restrict__ out, int n) {
    __shared__ uint4 zt[64 * 9];                       // z tile, A-frag-linear, stride 9 uint4
    __shared__ ushort_t hid[64 * HSTRIDE];             // hidden tile
    __shared__ ushort_t h3t[LAST ? 64 * 68 : 1];       // h3 tile (LAST only)

    int tid = threadIdx.x;
    int w = tid >> 6, lane = tid & 63;
    int g = lane >> 3, sub = lane & 7;
    int m = lane & 15, q = lane >> 4;
    int nb = blockIdx.x * 64;

    // zero hid k-pad cols 104..135 (barriered by the phase-A syncthreads)
    for (int i = tid; i < 64 * 32; i += 256) {
        int r = i >> 5, c = HID2 + (i & 31);
        hid[r * HSTRIDE + c] = 0;
    }

    float sc = 1.0f + eps[0];
    // ---- phase A: aggregate 16 nodes per wave into zt ----
    for (int i = 0; i < 16; i++) {
        int node = nb + w * 16 + i;
        int nc = min(node, n - 1);
        int beg = nrs[nc];
        int total = ndeg[nc];
        const ushort_t* hsub = hbin + sub * 8;
        const int* ss = srcsorted + beg + g;

        f32x2 A0 = {0,0}, A1 = {0,0}, A2 = {0,0}, A3 = {0,0};
        f32x2 B0 = {0,0}, B1 = {0,0}, B2 = {0,0}, B3 = {0,0};
        if (total > 0) {
            int f0 = ss[0], f1 = ss[8], f2r = ss[16], f3r = ss[24];
            for (int b = 0; b < total; b += 32) {
                bool ok = (b + 16) < total;
                int e0 = f0, e1 = f1;
                int e2 = ok ? f2r : n;
                int e3 = ok ? f3r : n;
                f0 = ss[b + 32]; f1 = ss[b + 40]; f2r = ss[b + 48]; f3r = ss[b + 56];
                uint4 v0 = *(const uint4*)(hsub + (size_t)e0 * 64);
                uint4 v1 = *(const uint4*)(hsub + (size_t)e1 * 64);
                uint4 v2 = *(const uint4*)(hsub + (size_t)e2 * 64);
                uint4 v3 = *(const uint4*)(hsub + (size_t)e3 * 64);
                A0 += unpk(v0.x); A1 += unpk(v0.y); A2 += unpk(v0.z); A3 += unpk(v0.w);
                B0 += unpk(v1.x); B1 += unpk(v1.y); B2 += unpk(v1.z); B3 += unpk(v1.w);
                A0 += unpk(v2.x); A1 += unpk(v2.y); A2 += unpk(v2.z); A3 += unpk(v2.w);
                B0 += unpk(v3.x); B1 += unpk(v3.y); B2 += unpk(v3.z); B3 += unpk(v3.w);
            }
        }
        A0 += B0; A1 += B1; A2 += B2; A3 += B3;
        float a0 = A0.x, a1 = A0.y, a2 = A1.x, a3 = A1.y;
        float a4 = A2.x, a5 = A2.y, a6 = A3.x, a7 = A3.y;
#pragma unroll
        for (int msk = 8; msk <= 32; msk <<= 1) {
            a0 += __shfl_xor(a0, msk); a1 += __shfl_xor(a1, msk);
            a2 += __shfl_xor(a2, msk); a3 += __shfl_xor(a3, msk);
            a4 += __shfl_xor(a4, msk); a5 += __shfl_xor(a5, msk);
            a6 += __shfl_xor(a6, msk); a7 += __shfl_xor(a7, msk);
        }
        if (lane < 8) {
            uint4 sv = *(const uint4*)(hbin + (size_t)nc * 64 + lane * 8);
            float o0 = fmaf(sc, bflo(sv.x), a0), o1 = fmaf(sc, bfhi(sv.x), a1);
            float o2 = fmaf(sc, bflo(sv.y), a2), o3 = fmaf(sc, bfhi(sv.y), a3);
            float o4 = fmaf(sc, bflo(sv.z), a4), o5 = fmaf(sc, bfhi(sv.z), a5);
            float o6 = fmaf(sc, bflo(sv.w), a6), o7 = fmaf(sc, bfhi(sv.w), a7);
            uint4 u;
            u.x = (uint_t)f2bf(o0) | ((uint_t)f2bf(o1) << 16);
            u.y = (uint_t)f2bf(o2) | ((uint_t)f2bf(o3) << 16);
            u.z = (uint_t)f2bf(o4) | ((uint_t)f2bf(o5) << 16);
            u.w = (uint_t)f2bf(o6) | ((uint_t)f2bf(o7) << 16);
            zt[(w * 16 + i) * 9 + lane] = u;
        }
    }
    __syncthreads();

    // ---- phase B: GEMM1 [16x64] @ [64x112] ----
    f32x4 acc1[7];
#pragma unroll
    for (int ct = 0; ct < 7; ct++) {
        int col = ct * 16 + m;
        float bv = (col < HID2) ? b1[col] : 0.f;
        acc1[ct] = (f32x4){bv, bv, bv, bv};
    }
#pragma unroll
    for (int ks = 0; ks < 2; ks++) {
        bf16x8 a = *(const bf16x8*)&zt[(w * 16 + m) * 9 + ks * 4 + q];
#pragma unroll
        for (int ct = 0; ct < 7; ct++) {
            bf16x8 b = *(const bf16x8*)(w1f + ((size_t)(ct * 2 + ks) * 64 + lane) * 8);
            acc1[ct] = __builtin_amdgcn_mfma_f32_16x16x32_bf16(a, b, acc1[ct], 0, 0, 0);
        }
    }
#pragma unroll
    for (int ct = 0; ct < 7; ct++) {
#pragma unroll
        for (int r = 0; r < 4; r++) {
            float v = fmaxf(acc1[ct][r], 0.f);
            int row = w * 16 + q * 4 + r;
            hid[row * HSTRIDE + ct * 16 + m] = f2bf(v);
        }
    }
    // ---- GEMM2 [16x128] @ [128x64] ----
    f32x4 acc2[4];
#pragma unroll
    for (int ct = 0; ct < 4; ct++) {
        int col = ct * 16 + m;
        float bv = (col < HID) ? b2[col] : 0.f;
        acc2[ct] = (f32x4){bv, bv, bv, bv};
    }
#pragma unroll
    for (int ks = 0; ks < 4; ks++) {
        bf16x8 a = *(const bf16x8*)&hid[(w * 16 + m) * HSTRIDE + ks * 32 + q * 8];
#pragma unroll
        for (int ct = 0; ct < 4; ct++) {
            bf16x8 b = *(const bf16x8*)(w2f + ((size_t)(ct * 4 + ks) * 64 + lane) * 8);
            acc2[ct] = __builtin_amdgcn_mfma_f32_16x16x32_bf16(a, b, acc2[ct], 0, 0, 0);
        }
    }

    if (!LAST) {
        // outer relu -> hbout bf16 [N][64]
#pragma unroll
        for (int ct = 0; ct < 4; ct++) {
#pragma unroll
            for (int r = 0; r < 4; r++) {
                int node = nb + w * 16 + q * 4 + r;
                if (node < n) {
                    float v = fmaxf(acc2[ct][r], 0.f);
                    hbout[(size_t)node * 64 + ct * 16 + m] = f2bf(v);
                }
            }
        }
    } else {
        // h3 (C-layout) -> LDS tile (rows w*16.. owned by this wave; no barrier needed)
#pragma unroll
        for (int ct = 0; ct < 4; ct++) {
#pragma unroll
            for (int r = 0; r < 4; r++) {
                float v = fmaxf(acc2[ct][r], 0.f);
                h3t[(w * 16 + q * 4 + r) * 68 + ct * 16 + m] = f2bf(v);
            }
        }
        // final: [16 x 256] @ [256 x 64] ; segs x,h1,h2 from global, h3 from LDS
        f32x4 accF[4];
#pragma unroll
        for (int ct = 0; ct < 4; ct++) {
            int col = ct * 16 + m;
            float bv = (col < HID) ? lin_b[col] : 0.f;
            accF[ct] = (f32x4){bv, bv, bv, bv};
        }
        int nodeA = min(nb + w * 16 + m, n - 1);
        const ushort_t* segs[3] = {xb, h1b, hbin};   // hbin == h2b in the last layer
#pragma unroll
        for (int ks = 0; ks < 8; ks++) {
            bf16x8 a;
            if (ks < 6) {
                const ushort_t* p = segs[ks >> 1];
                a = *(const bf16x8*)(p + (size_t)nodeA * 64 + (ks & 1) * 32 + q * 8);
            } else {
                a = *(const bf16x8*)&h3t[(w * 16 + m) * 68 + (ks & 1) * 32 + q * 8];
            }
#pragma unroll
            for (int ct = 0; ct < 4; ct++) {
                bf16x8 b = *(const bf16x8*)(linf + ((size_t)(ct * 8 + ks) * 64 + lane) * 8);
                accF[ct] = __builtin_amdgcn_mfma_f32_16x16x32_bf16(a, b, accF[ct], 0, 0, 0);
            }
        }
#pragma unroll
        for (int ct = 0; ct < 4; ct++) {
            int col = ct * 16 + m;
            if (col < HID) {
#pragma unroll
                for (int r = 0; r < 4; r++) {
                    int node = nb + w * 16 + q * 4 + r;
                    if (node < n)
                        out[(size_t)node * HID + col] = accF[ct][r];
                }
            }
        }
    }
}

extern "C" void kernel_launch(void* const* d_in, const int* in_sizes, int n_in,
                              void* d_out, int out_size, void* d_ws, size_t ws_size,
                              hipStream_t stream) {
    const float* x     = (const float*)d_in[0];
    const int*   ei    = (const int*)d_in[1];
    const float* w1    = (const float*)d_in[2];
    const float* b1    = (const float*)d_in[3];
    const float* w2    = (const float*)d_in[4];
    const float* b2    = (const float*)d_in[5];
    const float* eps   = (const float*)d_in[6];
    const float* lin_w = (const float*)d_in[7];
    const float* lin_b = (const float*)d_in[8];
    float* out = (float*)d_out;

    const int N = in_sizes[0] / HID;       // 100000
    const int E = in_sizes[1] / 2;         // 3200000
    const int* src = ei;
    const int* dst = ei + E;

    const int NBIN = (N + 255) / 256;      // 391

    // ---- workspace layout (16B-aligned blocks); gather tables have extra zero row N ----
    char* p = (char*)d_ws;
    const size_t ROWS = (size_t)(N + 1) * 64 * 2;
    ushort_t* xb  = (ushort_t*)p;  p += ROWS;
    ushort_t* h1b = (ushort_t*)p;  p += ROWS;
    ushort_t* h2b = (ushort_t*)p;  p += ROWS;
    ushort_t* w1f = (ushort_t*)p;  p += 3 * 14 * 512 * 2;
    ushort_t* w2f = (ushort_t*)p;  p += 3 * 16 * 512 * 2;
    ushort_t* linf= (ushort_t*)p;  p += 32 * 512 * 2;
    int* ghist    = (int*)p;       p += 528 * 4;
    int* binstart = (int*)p;       p += 528 * 4;
    int* gcur     = (int*)p;       p += 528 * 4;
    int* nrs      = (int*)p;       p += (size_t)(N + 4) * 4;
    int* ndeg     = (int*)p;       p += (size_t)(N + 4) * 4;
    uint_t* packed = (uint_t*)p;   p += (size_t)E * 4;
    int* srcsorted = (int*)p;      // E + NBIN*4096 + 64 entries (prefetch slack)

    const int BLK = 256;
    const int NP1 = (E + P1_CHUNK - 1) / P1_CHUNK;   // 391
    const int NXBLK = (N * 16 + BLK - 1) / BLK;      // 6250
    const int NBUCK = (N + 63) / 64;                 // 1563
    dim3 blk(BLK);

    // ---- fused setup (also zeroes ghist) then CSR build ----
    setup_kernel<<<NXBLK + 1 + 31, blk, 0, stream>>>(x, w1, w2, lin_w,
                                                     xb, h1b, h2b,
                                                     w1f, w2f, linf, ghist, N, NXBLK);
    bhist_kernel<<<NP1, blk, 0, stream>>>(dst, ghist, E);
    bscan_kernel<<<1, blk, 0, stream>>>(ghist, binstart, gcur, NBIN, E);
    pass1_kernel<<<NP1, blk, 0, stream>>>(src, dst, gcur, packed, E);
    pass2_kernel<<<NBIN, blk, 0, stream>>>(packed, binstart, srcsorted, nrs, ndeg, N);

    // ---- fused layers ----
    layer_kernel<0><<<NBUCK, blk, 0, stream>>>(xb, nrs, ndeg, srcsorted, eps + 0,
                                               w1f + 0 * 14 * 512, b1 + 0 * HID2,
                                               w2f + 0 * 16 * 512, b2 + 0 * HID,
                                               h1b, nullptr, nullptr, nullptr, nullptr,
                                               nullptr, N);
    layer_kernel<0><<<NBUCK, blk, 0, stream>>>(h1b, nrs, ndeg, srcsorted, eps + 1,
                                               w1f + 1 * 14 * 512, b1 + 1 * HID2,
                                               w2f + 1 * 16 * 512, b2 + 1 * HID,
                                               h2b, nullptr, nullptr, nullptr, nullptr,
                                               nullptr, N);
    layer_kernel<1><<<NBUCK, blk, 0, stream>>>(h2b, nrs, ndeg, srcsorted, eps + 2,
                                               w1f + 2 * 14 * 512, b1 + 2 * HID2,
                                               w2f + 2 * 16 * 512, b2 + 2 * HID,
                                               nullptr, xb, h1b,
                                               linf, lin_b, out, N);
}

// Round 10
// 407.277 us; speedup vs baseline: 1.1409x; 1.1409x over previous
//
#include <hip/hip_runtime.h>

#define HID 52
#define HID2 104
#define P1_CHUNK 8192
#define NBIN_MAX 512      // bins of 256 nodes; N <= 131072
#define HSTRIDE 136

typedef unsigned short ushort_t;
typedef unsigned int uint_t;
typedef short bf16x8 __attribute__((ext_vector_type(8)));
typedef float f32x4 __attribute__((ext_vector_type(4)));
typedef float f32x2 __attribute__((ext_vector_type(2)));

__device__ __forceinline__ ushort_t f2bf(float f) {
    union { float f; uint_t u; } c; c.f = f;
    uint_t u = c.u + 0x7FFFu + ((c.u >> 16) & 1u);   // RNE
    return (ushort_t)(u >> 16);
}
__device__ __forceinline__ float bflo(uint_t u) {
    union { uint_t u; float f; } c; c.u = u << 16; return c.f;
}
__device__ __forceinline__ float bfhi(uint_t u) {
    union { uint_t u; float f; } c; c.u = u & 0xFFFF0000u; return c.f;
}
__device__ __forceinline__ f32x2 unpk(uint_t u) {
    return (f32x2){bflo(u), bfhi(u)};
}

// ---------- fused setup: conv_x + zero pad rows + conv_w + bhist ----------
// ghist/gcnt are pre-zeroed by a hipMemsetAsync before this kernel.
__global__ __launch_bounds__(256) void setup_kernel(const float* __restrict__ x,
                                                    const float* __restrict__ w1,
                                                    const float* __restrict__ w2,
                                                    const float* __restrict__ lin_w,
                                                    const int* __restrict__ dst,
                                                    ushort_t* __restrict__ xb,
                                                    ushort_t* __restrict__ h1b,
                                                    ushort_t* __restrict__ h2b,
                                                    ushort_t* __restrict__ h3b,
                                                    ushort_t* __restrict__ w1f,
                                                    ushort_t* __restrict__ w2f,
                                                    ushort_t* __restrict__ linf,
                                                    int* __restrict__ ghist,
                                                    int n, int E, int nxblk) {
    __shared__ int lh[NBIN_MAX];
    int blk = blockIdx.x;
    int tid = threadIdx.x;
    if (blk < nxblk) {
        int t = blk * 256 + tid;
        if (t >= n * 16) return;
        int node = t >> 4, pp = t & 15;
        int c0 = pp * 4;
        ushort_t o[4];
#pragma unroll
        for (int j = 0; j < 4; j++) {
            int c = c0 + j;
            o[j] = (c < HID) ? f2bf(x[(size_t)node * HID + c]) : 0;
        }
        uint_t u0 = (uint_t)o[0] | ((uint_t)o[1] << 16);
        uint_t u1 = (uint_t)o[2] | ((uint_t)o[3] << 16);
        *(uint2*)(xb + (size_t)node * 64 + c0) = make_uint2(u0, u1);
        return;
    }
    if (blk == nxblk) {
        ushort_t* arr = (tid < 64) ? xb : (tid < 128) ? h1b : (tid < 192) ? h2b : h3b;
        arr[(size_t)n * 64 + (tid & 63)] = 0;
        return;
    }
    if (blk < nxblk + 32) {
        int gid = (blk - nxblk - 1) * 4 + (tid >> 6);
        int lane = tid & 63;
        if (gid >= 122) return;
        int m = lane & 15, q = lane >> 4;
        ushort_t o[8];
        ushort_t* dstp;
        if (gid < 42) {
            int l = gid / 14, r = gid % 14, ct = r >> 1, ks = r & 1;
            int nn = ct * 16 + m;
#pragma unroll
            for (int j = 0; j < 8; j++) {
                int k = ks * 32 + q * 8 + j;
                o[j] = (k < HID && nn < HID2) ? f2bf(w1[((size_t)l * HID + k) * HID2 + nn]) : 0;
            }
            dstp = w1f + ((size_t)(l * 14 + ct * 2 + ks) * 64 + lane) * 8;
        } else if (gid < 90) {
            int g2 = gid - 42, l = g2 / 16, r = g2 % 16, ct = r >> 2, ks = r & 3;
            int nn = ct * 16 + m;
#pragma unroll
            for (int j = 0; j < 8; j++) {
                int k = ks * 32 + q * 8 + j;
                o[j] = (k < HID2 && nn < HID) ? f2bf(w2[((size_t)l * HID2 + k) * HID + nn]) : 0;
            }
            dstp = w2f + ((size_t)(l * 16 + ct * 4 + ks) * 64 + lane) * 8;
        } else {
            int g2 = gid - 90, ct = g2 >> 3, ks = g2 & 7;
            int nn = ct * 16 + m;
#pragma unroll
            for (int j = 0; j < 8; j++) {
                int kg = ks * 32 + q * 8 + j;
                int seg = kg >> 6, kk = kg & 63;
                o[j] = (kk < HID && nn < HID) ? f2bf(lin_w[((size_t)seg * HID + kk) * HID + nn]) : 0;
            }
            dstp = linf + ((size_t)(ct * 8 + ks) * 64 + lane) * 8;
        }
        uint4 u;
        u.x = (uint_t)o[0] | ((uint_t)o[1] << 16);
        u.y = (uint_t)o[2] | ((uint_t)o[3] << 16);
        u.z = (uint_t)o[4] | ((uint_t)o[5] << 16);
        u.w = (uint_t)o[6] | ((uint_t)o[7] << 16);
        *(uint4*)dstp = u;
        return;
    }
    // ---- bhist section ----
    int eblk = blk - nxblk - 32;
    lh[tid] = 0; lh[tid + 256] = 0;
    __syncthreads();
    int base = eblk * P1_CHUNK;
    int cend = min(P1_CHUNK, E - base);
    for (int i = tid; i < cend; i += 256) atomicAdd(&lh[dst[base + i] >> 8], 1);
    __syncthreads();
    int cc = lh[tid];       if (cc) atomicAdd(&ghist[tid], cc);
    cc = lh[tid + 256];     if (cc) atomicAdd(&ghist[tid + 256], cc);
}

// ---------- pass 1: bin-partition edges with LDS staging; in-kernel binstart scan ----------
__global__ __launch_bounds__(256) void pass1_kernel(const int* __restrict__ src,
                                                    const int* __restrict__ dst,
                                                    const int* __restrict__ ghist,
                                                    int* __restrict__ gcnt,
                                                    uint_t* __restrict__ packed, int E) {
    __shared__ uint_t stage[P1_CHUNK];
    __shared__ ushort_t sbin[P1_CHUNK];
    __shared__ int gh[NBIN_MAX];
    __shared__ int cnt[NBIN_MAX];
    __shared__ int sst[NBIN_MAX];
    __shared__ int curs[NBIN_MAX];
    __shared__ int gbase[NBIN_MAX];
    __shared__ int ps[256];
    int tid = threadIdx.x;
    int b0 = 2 * tid, b1 = 2 * tid + 1;
    gh[b0] = ghist[b0]; gh[b1] = ghist[b1];
    cnt[tid] = 0; cnt[tid + 256] = 0;
    __syncthreads();
    // global exclusive scan -> bst0/bst1 (registers)
    int gpair = gh[b0] + gh[b1];
    ps[tid] = gpair;
    __syncthreads();
    for (int off = 1; off < 256; off <<= 1) {
        int t = (tid >= off) ? ps[tid - off] : 0;
        __syncthreads();
        ps[tid] += t;
        __syncthreads();
    }
    int bst0 = ps[tid] - gpair;
    int bst1 = bst0 + gh[b0];
    __syncthreads();
    // local chunk histogram
    int base = blockIdx.x * P1_CHUNK;
    int cend = min(P1_CHUNK, E - base);
    for (int i = tid; i < cend; i += 256) atomicAdd(&cnt[dst[base + i] >> 8], 1);
    __syncthreads();
    int c0 = cnt[b0], c1 = cnt[b1];
    int pair = c0 + c1;
    ps[tid] = pair;
    __syncthreads();
    for (int off = 1; off < 256; off <<= 1) {
        int t = (tid >= off) ? ps[tid - off] : 0;
        __syncthreads();
        ps[tid] += t;
        __syncthreads();
    }
    int ex = ps[tid] - pair;
    sst[b0] = ex;       curs[b0] = ex;
    sst[b1] = ex + c0;  curs[b1] = ex + c0;
    gbase[b0] = c0 ? (bst0 + atomicAdd(&gcnt[b0], c0)) : 0;
    gbase[b1] = c1 ? (bst1 + atomicAdd(&gcnt[b1], c1)) : 0;
    __syncthreads();
    for (int i = tid; i < cend; i += 256) {
        int d = dst[base + i];
        int s = src[base + i];
        int b = d >> 8;
        int pos = atomicAdd(&curs[b], 1);
        stage[pos] = ((uint_t)s << 8) | (uint_t)(d & 255);
        sbin[pos] = (ushort_t)b;
    }
    __syncthreads();
    for (int i = tid; i < cend; i += 256) {
        int b = sbin[i];
        packed[gbase[b] + (i - sst[b])] = stage[i];
    }
}

// ---------- pass 2: per-bin counting sort with composite key (node, src>>15) ----------
// -> srcsorted node runs, src-range-ordered within each node, padded to x16 (zero-row N)
__global__ __launch_bounds__(256) void pass2_kernel(const uint_t* __restrict__ packed,
                                                    const int* __restrict__ ghist,
                                                    int* __restrict__ srcsorted,
                                                    int* __restrict__ nrs,
                                                    int* __restrict__ ndeg, int N) {
    __shared__ int c[NBIN_MAX];
    __shared__ int ps[256];
    __shared__ int hist[1024];
    __shared__ int curs[1024];
    int b = blockIdx.x;
    int tid = threadIdx.x;
    int b0 = 2 * tid, b1 = 2 * tid + 1;
    c[b0] = ghist[b0]; c[b1] = ghist[b1];
    hist[tid] = 0; hist[tid + 256] = 0; hist[tid + 512] = 0; hist[tid + 768] = 0;
    __syncthreads();
    int gpair = c[b0] + c[b1];
    ps[tid] = gpair;
    __syncthreads();
    for (int off = 1; off < 256; off <<= 1) {
        int t = (tid >= off) ? ps[tid - off] : 0;
        __syncthreads();
        ps[tid] += t;
        __syncthreads();
    }
    // exclusive binstart for bins b0,b1 stored back into c (no longer need raw counts there)
    int e0 = ps[tid] - gpair;
    int cntb0 = c[b0], cntb1 = c[b1];
    __syncthreads();
    c[b0] = e0;
    c[b1] = e0 + cntb0;
    __syncthreads();
    int beg = c[b];
    int cntb = (b == b0) ? cntb0 : 0;   // dummy; recomputed below properly
    // NOTE: every thread needs beg/end of THIS block's bin:
    cntb = ghist[b];
    int end = beg + cntb;
    int obase = beg + b * 4096;
    // (node, range) histogram
    for (int i = beg + tid; i < end; i += 256) {
        uint_t p = packed[i];
        int key = ((int)(p & 255u) << 2) | (int)((p >> 8) >> 15);
        atomicAdd(&hist[key], 1);
    }
    __syncthreads();
    int h0 = hist[tid * 4], h1 = hist[tid * 4 + 1], h2 = hist[tid * 4 + 2], h3 = hist[tid * 4 + 3];
    int v = h0 + h1 + h2 + h3;
    int pv = (v + 15) & ~15;
    ps[tid] = pv;
    __syncthreads();
    for (int off = 1; off < 256; off <<= 1) {
        int t = (tid >= off) ? ps[tid - off] : 0;
        __syncthreads();
        ps[tid] += t;
        __syncthreads();
    }
    int start = obase + ps[tid] - pv;
    int node = b * 256 + tid;
    if (node < N) { nrs[node] = start; ndeg[node] = pv; }
    curs[tid * 4 + 0] = start;
    curs[tid * 4 + 1] = start + h0;
    curs[tid * 4 + 2] = start + h0 + h1;
    curs[tid * 4 + 3] = start + h0 + h1 + h2;
    __syncthreads();
    for (int i = beg + tid; i < end; i += 256) {
        uint_t p = packed[i];
        int s = (int)(p >> 8);
        int key = ((int)(p & 255u) << 2) | (s >> 15);
        int pos = atomicAdd(&curs[key], 1);
        srcsorted[pos] = s;
    }
    __syncthreads();
    for (int i = start + v; i < start + pv; i++) srcsorted[i] = N;   // zero-row pads
}

// ---------- aggregation: wave/node, direct idx loads, 4 rows in flight (R8) ----------
__global__ __launch_bounds__(256) void agg_kernel(const ushort_t* __restrict__ hb,
                                                  const int* __restrict__ nrs,
                                                  const int* __restrict__ ndeg,
                                                  const int* __restrict__ srcsorted,
                                                  const float* __restrict__ eps,
                                                  ushort_t* __restrict__ zb, int n) {
    int wid = (blockIdx.x * blockDim.x + threadIdx.x) >> 6;
    if (wid >= n) return;
    int lane = threadIdx.x & 63;
    int g = lane >> 3, sub = lane & 7;
    int beg = nrs[wid];
    int total = ndeg[wid];               // multiple of 16 (pads -> zero row N)
    const ushort_t* hsub = hb + sub * 8;
    const int* ss = srcsorted + beg + g;

    f32x2 A0 = {0,0}, A1 = {0,0}, A2 = {0,0}, A3 = {0,0};
    f32x2 B0 = {0,0}, B1 = {0,0}, B2 = {0,0}, B3 = {0,0};
    if (total > 0) {
        int f0 = ss[0], f1 = ss[8], f2r = ss[16], f3r = ss[24];
        for (int b = 0; b < total; b += 32) {
            bool ok = (b + 16) < total;
            int e0 = f0, e1 = f1;
            int e2 = ok ? f2r : n;
            int e3 = ok ? f3r : n;
            f0 = ss[b + 32]; f1 = ss[b + 40]; f2r = ss[b + 48]; f3r = ss[b + 56];
            uint4 v0 = *(const uint4*)(hsub + (size_t)e0 * 64);
            uint4 v1 = *(const uint4*)(hsub + (size_t)e1 * 64);
            uint4 v2 = *(const uint4*)(hsub + (size_t)e2 * 64);
            uint4 v3 = *(const uint4*)(hsub + (size_t)e3 * 64);
            A0 += unpk(v0.x); A1 += unpk(v0.y); A2 += unpk(v0.z); A3 += unpk(v0.w);
            B0 += unpk(v1.x); B1 += unpk(v1.y); B2 += unpk(v1.z); B3 += unpk(v1.w);
            A0 += unpk(v2.x); A1 += unpk(v2.y); A2 += unpk(v2.z); A3 += unpk(v2.w);
            B0 += unpk(v3.x); B1 += unpk(v3.y); B2 += unpk(v3.z); B3 += unpk(v3.w);
        }
    }
    A0 += B0; A1 += B1; A2 += B2; A3 += B3;
    float a0 = A0.x, a1 = A0.y, a2 = A1.x, a3 = A1.y;
    float a4 = A2.x, a5 = A2.y, a6 = A3.x, a7 = A3.y;
#pragma unroll
    for (int msk = 8; msk <= 32; msk <<= 1) {
        a0 += __shfl_xor(a0, msk); a1 += __shfl_xor(a1, msk);
        a2 += __shfl_xor(a2, msk); a3 += __shfl_xor(a3, msk);
        a4 += __shfl_xor(a4, msk); a5 += __shfl_xor(a5, msk);
        a6 += __shfl_xor(a6, msk); a7 += __shfl_xor(a7, msk);
    }
    if (lane < 8) {
        float sc = 1.0f + eps[0];
        uint4 sv = *(const uint4*)(hb + (size_t)wid * 64 + lane * 8);
        float o0 = fmaf(sc, bflo(sv.x), a0), o1 = fmaf(sc, bfhi(sv.x), a1);
        float o2 = fmaf(sc, bflo(sv.y), a2), o3 = fmaf(sc, bfhi(sv.y), a3);
        float o4 = fmaf(sc, bflo(sv.z), a4), o5 = fmaf(sc, bfhi(sv.z), a5);
        float o6 = fmaf(sc, bflo(sv.w), a6), o7 = fmaf(sc, bfhi(sv.w), a7);
        uint4 u;
        u.x = (uint_t)f2bf(o0) | ((uint_t)f2bf(o1) << 16);
        u.y = (uint_t)f2bf(o2) | ((uint_t)f2bf(o3) << 16);
        u.z = (uint_t)f2bf(o4) | ((uint_t)f2bf(o5) << 16);
        u.w = (uint_t)f2bf(o6) | ((uint_t)f2bf(o7) << 16);
        *(uint4*)(zb + (size_t)wid * 64 + lane * 8) = u;
    }
}

// ---------- MFMA fused 2-layer MLP (R8) ----------
__global__ __launch_bounds__(256) void mlp_kernel(const ushort_t* __restrict__ zb,
                                                  const ushort_t* __restrict__ w1f,
                                                  const float* __restrict__ b1,
                                                  const ushort_t* __restrict__ w2f,
                                                  const float* __restrict__ b2,
                                                  ushort_t* __restrict__ hbout, int n) {
    __shared__ ushort_t hid[64 * HSTRIDE];
    int tid = threadIdx.x;
    int w = tid >> 6, lane = tid & 63, m = lane & 15, q = lane >> 4;
    for (int i = tid; i < 64 * 32; i += 256) {
        int r = i >> 5, c = HID2 + (i & 31);
        hid[r * HSTRIDE + c] = 0;
    }
    __syncthreads();

    int nb = blockIdx.x * 64 + w * 16;
    f32x4 acc1[7];
#pragma unroll
    for (int ct = 0; ct < 7; ct++) {
        int col = ct * 16 + m;
        float bv = (col < HID2) ? b1[col] : 0.f;
        acc1[ct] = (f32x4){bv, bv, bv, bv};
    }
    int anode = min(nb + m, n - 1);
#pragma unroll
    for (int ks = 0; ks < 2; ks++) {
        bf16x8 a = *(const bf16x8*)(zb + (size_t)anode * 64 + ks * 32 + q * 8);
#pragma unroll
        for (int ct = 0; ct < 7; ct++) {
            bf16x8 b = *(const bf16x8*)(w1f + ((size_t)(ct * 2 + ks) * 64 + lane) * 8);
            acc1[ct] = __builtin_amdgcn_mfma_f32_16x16x32_bf16(a, b, acc1[ct], 0, 0, 0);
        }
    }
#pragma unroll
    for (int ct = 0; ct < 7; ct++) {
#pragma unroll
        for (int r = 0; r < 4; r++) {
            float v = fmaxf(acc1[ct][r], 0.f);
            int row = w * 16 + q * 4 + r;
            hid[row * HSTRIDE + ct * 16 + m] = f2bf(v);
        }
    }
    f32x4 acc2[4];
#pragma unroll
    for (int ct = 0; ct < 4; ct++) {
        int col = ct * 16 + m;
        float bv = (col < HID) ? b2[col] : 0.f;
        acc2[ct] = (f32x4){bv, bv, bv, bv};
    }
#pragma unroll
    for (int ks = 0; ks < 4; ks++) {
        bf16x8 a = *(const bf16x8*)&hid[(w * 16 + m) * HSTRIDE + ks * 32 + q * 8];
#pragma unroll
        for (int ct = 0; ct < 4; ct++) {
            bf16x8 b = *(const bf16x8*)(w2f + ((size_t)(ct * 4 + ks) * 64 + lane) * 8);
            acc2[ct] = __builtin_amdgcn_mfma_f32_16x16x32_bf16(a, b, acc2[ct], 0, 0, 0);
        }
    }
#pragma unroll
    for (int ct = 0; ct < 4; ct++) {
#pragma unroll
        for (int r = 0; r < 4; r++) {
            int node = nb + q * 4 + r;
            if (node < n) {
                float v = fmaxf(acc2[ct][r], 0.f);
                hbout[(size_t)node * 64 + ct * 16 + m] = f2bf(v);
            }
        }
    }
}

// ---------- MFMA final (R8) ----------
__global__ __launch_bounds__(256) void final_kernel(const ushort_t* __restrict__ xb,
                                                    const ushort_t* __restrict__ h1b,
                                                    const ushort_t* __restrict__ h2b,
                                                    const ushort_t* __restrict__ h3b,
                                                    const ushort_t* __restrict__ linf,
                                                    const float* __restrict__ lin_b,
                                                    float* __restrict__ out, int ntiles) {
    int tid = threadIdx.x;
    int w = tid >> 6, lane = tid & 63, m = lane & 15, q = lane >> 4;
    int tile = blockIdx.x * 4 + w;
    if (tile >= ntiles) return;
    int nb = tile * 16;
    const ushort_t* segs[4] = {xb, h1b, h2b, h3b};
    f32x4 acc[4];
#pragma unroll
    for (int ct = 0; ct < 4; ct++) {
        int col = ct * 16 + m;
        float bv = (col < HID) ? lin_b[col] : 0.f;
        acc[ct] = (f32x4){bv, bv, bv, bv};
    }
#pragma unroll
    for (int ks = 0; ks < 8; ks++) {
        const ushort_t* p = segs[ks >> 1];
        bf16x8 a = *(const bf16x8*)(p + (size_t)(nb + m) * 64 + (ks & 1) * 32 + q * 8);
#pragma unroll
        for (int ct = 0; ct < 4; ct++) {
            bf16x8 b = *(const bf16x8*)(linf + ((size_t)(ct * 8 + ks) * 64 + lane) * 8);
            acc[ct] = __builtin_amdgcn_mfma_f32_16x16x32_bf16(a, b, acc[ct], 0, 0, 0);
        }
    }
#pragma unroll
    for (int ct = 0; ct < 4; ct++) {
        int col = ct * 16 + m;
        if (col < HID) {
#pragma unroll
            for (int r = 0; r < 4; r++)
                out[(size_t)(nb + q * 4 + r) * HID + col] = acc[ct][r];
        }
    }
}

extern "C" void kernel_launch(void* const* d_in, const int* in_sizes, int n_in,
                              void* d_out, int out_size, void* d_ws, size_t ws_size,
                              hipStream_t stream) {
    const float* x     = (const float*)d_in[0];
    const int*   ei    = (const int*)d_in[1];
    const float* w1    = (const float*)d_in[2];
    const float* b1    = (const float*)d_in[3];
    const float* w2    = (const float*)d_in[4];
    const float* b2    = (const float*)d_in[5];
    const float* eps   = (const float*)d_in[6];
    const float* lin_w = (const float*)d_in[7];
    const float* lin_b = (const float*)d_in[8];
    float* out = (float*)d_out;

    const int N = in_sizes[0] / HID;       // 100000
    const int E = in_sizes[1] / 2;         // 3200000
    const int* src = ei;
    const int* dst = ei + E;

    const int NBIN = (N + 255) / 256;      // 391

    // ---- workspace layout (16B-aligned blocks); gather tables have extra zero row N ----
    char* p = (char*)d_ws;
    const size_t ROWS = (size_t)(N + 1) * 64 * 2;
    ushort_t* xb  = (ushort_t*)p;  p += ROWS;
    ushort_t* zb  = (ushort_t*)p;  p += ROWS;
    ushort_t* h1b = (ushort_t*)p;  p += ROWS;
    ushort_t* h2b = (ushort_t*)p;  p += ROWS;
    ushort_t* h3b = (ushort_t*)p;  p += ROWS;
    ushort_t* w1f = (ushort_t*)p;  p += 3 * 14 * 512 * 2;
    ushort_t* w2f = (ushort_t*)p;  p += 3 * 16 * 512 * 2;
    ushort_t* linf= (ushort_t*)p;  p += 32 * 512 * 2;
    int* ghist    = (int*)p;       p += 512 * 4;
    int* gcnt     = (int*)p;       p += 512 * 4;     // contiguous with ghist for one memset
    int* nrs      = (int*)p;       p += (size_t)(N + 4) * 4;
    int* ndeg     = (int*)p;       p += (size_t)(N + 4) * 4;
    uint_t* packed = (uint_t*)p;   p += (size_t)E * 4;
    int* srcsorted = (int*)p;      // E + NBIN*4096 + 64 entries (prefetch slack)

    ushort_t* hbs[4] = {xb, h1b, h2b, h3b};

    const int BLK = 256;
    const int NP1 = (E + P1_CHUNK - 1) / P1_CHUNK;   // 391
    const int NXBLK = (N * 16 + BLK - 1) / BLK;      // 6250
    const int NBUCK = (N + 63) / 64;                 // 1563
    dim3 blk(BLK);
    dim3 grid_agg(((size_t)N * 64 + BLK - 1) / BLK);

    // ---- setup (conv + bhist fused) then 2-pass radix CSR build ----
    hipMemsetAsync(ghist, 0, 1024 * sizeof(int), stream);   // ghist + gcnt
    setup_kernel<<<NXBLK + 32 + NP1, blk, 0, stream>>>(x, w1, w2, lin_w, dst,
                                                       xb, h1b, h2b, h3b,
                                                       w1f, w2f, linf, ghist, N, E, NXBLK);
    pass1_kernel<<<NP1, blk, 0, stream>>>(src, dst, ghist, gcnt, packed, E);
    pass2_kernel<<<NBIN, blk, 0, stream>>>(packed, ghist, srcsorted, nrs, ndeg, N);

    // ---- layers ----
    for (int l = 0; l < 3; l++) {
        agg_kernel<<<grid_agg, blk, 0, stream>>>(hbs[l], nrs, ndeg, srcsorted, eps + l, zb, N);
        mlp_kernel<<<NBUCK, blk, 0, stream>>>(zb,
                                              w1f + (size_t)l * 14 * 512,
                                              b1 + (size_t)l * HID2,
                                              w2f + (size_t)l * 16 * 512,
                                              b2 + (size_t)l * HID,
                                              hbs[l + 1], N);
    }
    final_kernel<<<(6250 + 3) / 4 + 1, blk, 0, stream>>>(xb, h1b, h2b, h3b, linf, lin_b,
                                                         out, (N + 15) / 16);
}

// Round 11
// 397.412 us; speedup vs baseline: 1.1692x; 1.0248x over previous
//
#include <hip/hip_runtime.h>

#define HID 52
#define HID2 104
#define P1_CHUNK 8192
#define NBIN_MAX 512      // bins of 256 nodes; N <= 131072
#define HSTRIDE 136

typedef unsigned short ushort_t;
typedef unsigned int uint_t;
typedef short bf16x8 __attribute__((ext_vector_type(8)));
typedef float f32x4 __attribute__((ext_vector_type(4)));
typedef float f32x2 __attribute__((ext_vector_type(2)));

__device__ __forceinline__ ushort_t f2bf(float f) {
    union { float f; uint_t u; } c; c.f = f;
    uint_t u = c.u + 0x7FFFu + ((c.u >> 16) & 1u);   // RNE
    return (ushort_t)(u >> 16);
}
__device__ __forceinline__ float bflo(uint_t u) {
    union { uint_t u; float f; } c; c.u = u << 16; return c.f;
}
__device__ __forceinline__ float bfhi(uint_t u) {
    union { uint_t u; float f; } c; c.u = u & 0xFFFF0000u; return c.f;
}
// "noisy" unpack: hi half reinterpreted directly (low bits = mantissa noise < 1 bf16 ulp)
__device__ __forceinline__ f32x2 unpk2(uint_t u) {
    union { uint_t u; float f; } lo, hi;
    lo.u = u << 16; hi.u = u;
    return (f32x2){lo.f, hi.f};
}

// ---------- fused setup: conv_x + zero pad rows + conv_w + bhist ----------
// ghist/gcnt are pre-zeroed by a hipMemsetAsync before this kernel.
__global__ __launch_bounds__(256) void setup_kernel(const float* __restrict__ x,
                                                    const float* __restrict__ w1,
                                                    const float* __restrict__ w2,
                                                    const float* __restrict__ lin_w,
                                                    const int* __restrict__ dst,
                                                    ushort_t* __restrict__ xb,
                                                    ushort_t* __restrict__ h1b,
                                                    ushort_t* __restrict__ h2b,
                                                    ushort_t* __restrict__ w1f,
                                                    ushort_t* __restrict__ w2f,
                                                    ushort_t* __restrict__ linf,
                                                    int* __restrict__ ghist,
                                                    int n, int E, int nxblk) {
    __shared__ int lh[NBIN_MAX];
    int blk = blockIdx.x;
    int tid = threadIdx.x;
    if (blk < nxblk) {
        int t = blk * 256 + tid;
        if (t >= n * 16) return;
        int node = t >> 4, pp = t & 15;
        int c0 = pp * 4;
        ushort_t o[4];
#pragma unroll
        for (int j = 0; j < 4; j++) {
            int c = c0 + j;
            o[j] = (c < HID) ? f2bf(x[(size_t)node * HID + c]) : 0;
        }
        uint_t u0 = (uint_t)o[0] | ((uint_t)o[1] << 16);
        uint_t u1 = (uint_t)o[2] | ((uint_t)o[3] << 16);
        *(uint2*)(xb + (size_t)node * 64 + c0) = make_uint2(u0, u1);
        return;
    }
    if (blk == nxblk) {
        ushort_t* arr = (tid < 64) ? xb : (tid < 128) ? h1b : h2b;  // 192-255 dup h2b: benign
        arr[(size_t)n * 64 + (tid & 63)] = 0;
        return;
    }
    if (blk < nxblk + 32) {
        int gid = (blk - nxblk - 1) * 4 + (tid >> 6);
        int lane = tid & 63;
        if (gid >= 122) return;
        int m = lane & 15, q = lane >> 4;
        ushort_t o[8];
        ushort_t* dstp;
        if (gid < 42) {
            int l = gid / 14, r = gid % 14, ct = r >> 1, ks = r & 1;
            int nn = ct * 16 + m;
#pragma unroll
            for (int j = 0; j < 8; j++) {
                int k = ks * 32 + q * 8 + j;
                o[j] = (k < HID && nn < HID2) ? f2bf(w1[((size_t)l * HID + k) * HID2 + nn]) : 0;
            }
            dstp = w1f + ((size_t)(l * 14 + ct * 2 + ks) * 64 + lane) * 8;
        } else if (gid < 90) {
            int g2 = gid - 42, l = g2 / 16, r = g2 % 16, ct = r >> 2, ks = r & 3;
            int nn = ct * 16 + m;
#pragma unroll
            for (int j = 0; j < 8; j++) {
                int k = ks * 32 + q * 8 + j;
                o[j] = (k < HID2 && nn < HID) ? f2bf(w2[((size_t)l * HID2 + k) * HID + nn]) : 0;
            }
            dstp = w2f + ((size_t)(l * 16 + ct * 4 + ks) * 64 + lane) * 8;
        } else {
            int g2 = gid - 90, ct = g2 >> 3, ks = g2 & 7;
            int nn = ct * 16 + m;
#pragma unroll
            for (int j = 0; j < 8; j++) {
                int kg = ks * 32 + q * 8 + j;
                int seg = kg >> 6, kk = kg & 63;
                o[j] = (kk < HID && nn < HID) ? f2bf(lin_w[((size_t)seg * HID + kk) * HID + nn]) : 0;
            }
            dstp = linf + ((size_t)(ct * 8 + ks) * 64 + lane) * 8;
        }
        uint4 u;
        u.x = (uint_t)o[0] | ((uint_t)o[1] << 16);
        u.y = (uint_t)o[2] | ((uint_t)o[3] << 16);
        u.z = (uint_t)o[4] | ((uint_t)o[5] << 16);
        u.w = (uint_t)o[6] | ((uint_t)o[7] << 16);
        *(uint4*)dstp = u;
        return;
    }
    // ---- bhist section ----
    int eblk = blk - nxblk - 32;
    lh[tid] = 0; lh[tid + 256] = 0;
    __syncthreads();
    int base = eblk * P1_CHUNK;
    int cend = min(P1_CHUNK, E - base);
    for (int i = tid; i < cend; i += 256) atomicAdd(&lh[dst[base + i] >> 8], 1);
    __syncthreads();
    int cc = lh[tid];       if (cc) atomicAdd(&ghist[tid], cc);
    cc = lh[tid + 256];     if (cc) atomicAdd(&ghist[tid + 256], cc);
}

// ---------- pass 1: bin-partition edges with LDS staging; in-kernel binstart scan ----------
__global__ __launch_bounds__(256) void pass1_kernel(const int* __restrict__ src,
                                                    const int* __restrict__ dst,
                                                    const int* __restrict__ ghist,
                                                    int* __restrict__ gcnt,
                                                    uint_t* __restrict__ packed, int E) {
    __shared__ uint_t stage[P1_CHUNK];
    __shared__ ushort_t sbin[P1_CHUNK];
    __shared__ int gh[NBIN_MAX];
    __shared__ int cnt[NBIN_MAX];
    __shared__ int sst[NBIN_MAX];
    __shared__ int curs[NBIN_MAX];
    __shared__ int gbase[NBIN_MAX];
    __shared__ int ps[256];
    int tid = threadIdx.x;
    int b0 = 2 * tid, b1 = 2 * tid + 1;
    gh[b0] = ghist[b0]; gh[b1] = ghist[b1];
    cnt[tid] = 0; cnt[tid + 256] = 0;
    __syncthreads();
    int gpair = gh[b0] + gh[b1];
    ps[tid] = gpair;
    __syncthreads();
    for (int off = 1; off < 256; off <<= 1) {
        int t = (tid >= off) ? ps[tid - off] : 0;
        __syncthreads();
        ps[tid] += t;
        __syncthreads();
    }
    int bst0 = ps[tid] - gpair;
    int bst1 = bst0 + gh[b0];
    __syncthreads();
    int base = blockIdx.x * P1_CHUNK;
    int cend = min(P1_CHUNK, E - base);
    for (int i = tid; i < cend; i += 256) atomicAdd(&cnt[dst[base + i] >> 8], 1);
    __syncthreads();
    int c0 = cnt[b0], c1 = cnt[b1];
    int pair = c0 + c1;
    ps[tid] = pair;
    __syncthreads();
    for (int off = 1; off < 256; off <<= 1) {
        int t = (tid >= off) ? ps[tid - off] : 0;
        __syncthreads();
        ps[tid] += t;
        __syncthreads();
    }
    int ex = ps[tid] - pair;
    sst[b0] = ex;       curs[b0] = ex;
    sst[b1] = ex + c0;  curs[b1] = ex + c0;
    gbase[b0] = c0 ? (bst0 + atomicAdd(&gcnt[b0], c0)) : 0;
    gbase[b1] = c1 ? (bst1 + atomicAdd(&gcnt[b1], c1)) : 0;
    __syncthreads();
    for (int i = tid; i < cend; i += 256) {
        int d = dst[base + i];
        int s = src[base + i];
        int b = d >> 8;
        int pos = atomicAdd(&curs[b], 1);
        stage[pos] = ((uint_t)s << 8) | (uint_t)(d & 255);
        sbin[pos] = (ushort_t)b;
    }
    __syncthreads();
    for (int i = tid; i < cend; i += 256) {
        int b = sbin[i];
        packed[gbase[b] + (i - sst[b])] = stage[i];
    }
}

// ---------- pass 2: per-bin counting sort (plain node key), padded runs ----------
__global__ __launch_bounds__(256) void pass2_kernel(const uint_t* __restrict__ packed,
                                                    const int* __restrict__ ghist,
                                                    int* __restrict__ srcsorted,
                                                    int* __restrict__ nrs,
                                                    int* __restrict__ ndeg, int N) {
    __shared__ int c[NBIN_MAX];
    __shared__ int ps[256];
    __shared__ int hist[256];
    __shared__ int curs[256];
    int b = blockIdx.x;
    int tid = threadIdx.x;
    int b0 = 2 * tid, b1 = 2 * tid + 1;
    int g0 = ghist[b0], g1 = ghist[b1];
    hist[tid] = 0;
    int gpair = g0 + g1;
    ps[tid] = gpair;
    __syncthreads();
    for (int off = 1; off < 256; off <<= 1) {
        int t = (tid >= off) ? ps[tid - off] : 0;
        __syncthreads();
        ps[tid] += t;
        __syncthreads();
    }
    int ex = ps[tid] - gpair;
    c[b0] = ex;
    c[b1] = ex + g0;
    __syncthreads();
    int beg = c[b];
    int end = beg + ghist[b];
    int obase = beg + b * 4096;
    for (int i = beg + tid; i < end; i += 256) atomicAdd(&hist[packed[i] & 255u], 1);
    __syncthreads();
    int v = hist[tid];
    int pv = (v + 15) & ~15;
    ps[tid] = pv;
    __syncthreads();
    for (int off = 1; off < 256; off <<= 1) {
        int t = (tid >= off) ? ps[tid - off] : 0;
        __syncthreads();
        ps[tid] += t;
        __syncthreads();
    }
    int start = obase + ps[tid] - pv;
    int node = b * 256 + tid;
    if (node < N) { nrs[node] = start; ndeg[node] = pv; }
    curs[tid] = start;
    __syncthreads();
    for (int i = beg + tid; i < end; i += 256) {
        uint_t p = packed[i];
        int pos = atomicAdd(&curs[p & 255u], 1);
        srcsorted[pos] = (int)(p >> 8);
    }
    __syncthreads();
    for (int i = start + v; i < start + pv; i++) srcsorted[i] = N;   // zero-row pads
}

// ---------- aggregation: wave/node, direct idx loads, 4 rows in flight, noisy unpack ----------
__global__ __launch_bounds__(256) void agg_kernel(const ushort_t* __restrict__ hb,
                                                  const int* __restrict__ nrs,
                                                  const int* __restrict__ ndeg,
                                                  const int* __restrict__ srcsorted,
                                                  const float* __restrict__ eps,
                                                  ushort_t* __restrict__ zb, int n) {
    int wid = (blockIdx.x * blockDim.x + threadIdx.x) >> 6;
    if (wid >= n) return;
    int lane = threadIdx.x & 63;
    int g = lane >> 3, sub = lane & 7;
    int beg = nrs[wid];
    int total = ndeg[wid];               // multiple of 16 (pads -> zero row N)
    const ushort_t* hsub = hb + sub * 8;
    const int* ss = srcsorted + beg + g;

    f32x2 A0 = {0,0}, A1 = {0,0}, A2 = {0,0}, A3 = {0,0};
    f32x2 B0 = {0,0}, B1 = {0,0}, B2 = {0,0}, B3 = {0,0};
    if (total > 0) {
        int f0 = ss[0], f1 = ss[8], f2r = ss[16], f3r = ss[24];
        for (int b = 0; b < total; b += 32) {
            bool ok = (b + 16) < total;
            int e0 = f0, e1 = f1;
            int e2 = ok ? f2r : n;
            int e3 = ok ? f3r : n;
            f0 = ss[b + 32]; f1 = ss[b + 40]; f2r = ss[b + 48]; f3r = ss[b + 56];
            uint4 v0 = *(const uint4*)(hsub + (size_t)e0 * 64);
            uint4 v1 = *(const uint4*)(hsub + (size_t)e1 * 64);
            uint4 v2 = *(const uint4*)(hsub + (size_t)e2 * 64);
            uint4 v3 = *(const uint4*)(hsub + (size_t)e3 * 64);
            A0 += unpk2(v0.x); A1 += unpk2(v0.y); A2 += unpk2(v0.z); A3 += unpk2(v0.w);
            B0 += unpk2(v1.x); B1 += unpk2(v1.y); B2 += unpk2(v1.z); B3 += unpk2(v1.w);
            A0 += unpk2(v2.x); A1 += unpk2(v2.y); A2 += unpk2(v2.z); A3 += unpk2(v2.w);
            B0 += unpk2(v3.x); B1 += unpk2(v3.y); B2 += unpk2(v3.z); B3 += unpk2(v3.w);
        }
    }
    A0 += B0; A1 += B1; A2 += B2; A3 += B3;
    float a0 = A0.x, a1 = A0.y, a2 = A1.x, a3 = A1.y;
    float a4 = A2.x, a5 = A2.y, a6 = A3.x, a7 = A3.y;
#pragma unroll
    for (int msk = 8; msk <= 32; msk <<= 1) {
        a0 += __shfl_xor(a0, msk); a1 += __shfl_xor(a1, msk);
        a2 += __shfl_xor(a2, msk); a3 += __shfl_xor(a3, msk);
        a4 += __shfl_xor(a4, msk); a5 += __shfl_xor(a5, msk);
        a6 += __shfl_xor(a6, msk); a7 += __shfl_xor(a7, msk);
    }
    if (lane < 8) {
        float sc = 1.0f + eps[0];
        uint4 sv = *(const uint4*)(hb + (size_t)wid * 64 + lane * 8);
        float o0 = fmaf(sc, bflo(sv.x), a0), o1 = fmaf(sc, bfhi(sv.x), a1);
        float o2 = fmaf(sc, bflo(sv.y), a2), o3 = fmaf(sc, bfhi(sv.y), a3);
        float o4 = fmaf(sc, bflo(sv.z), a4), o5 = fmaf(sc, bfhi(sv.z), a5);
        float o6 = fmaf(sc, bflo(sv.w), a6), o7 = fmaf(sc, bfhi(sv.w), a7);
        uint4 u;
        u.x = (uint_t)f2bf(o0) | ((uint_t)f2bf(o1) << 16);
        u.y = (uint_t)f2bf(o2) | ((uint_t)f2bf(o3) << 16);
        u.z = (uint_t)f2bf(o4) | ((uint_t)f2bf(o5) << 16);
        u.w = (uint_t)f2bf(o6) | ((uint_t)f2bf(o7) << 16);
        *(uint4*)(zb + (size_t)wid * 64 + lane * 8) = u;
    }
}

// ---------- MFMA fused 2-layer MLP; LAST=1 also fuses the final concat linear ----------
template<int LAST>
__global__ __launch_bounds__(256) void mlp_kernel(const ushort_t* __restrict__ zb,
                                                  const ushort_t* __restrict__ w1f,
                                                  const float* __restrict__ b1,
                                                  const ushort_t* __restrict__ w2f,
                                                  const float* __restrict__ b2,
                                                  ushort_t* __restrict__ hbout,
                                                  const ushort_t* __restrict__ xb,
                                                  const ushort_t* __restrict__ h1b,
                                                  const ushort_t* __restrict__ h2b,
                                                  const ushort_t* __restrict__ linf,
                                                  const float* __restrict__ lin_b,
                                                  float* __restrict__ out, int n) {
    __shared__ ushort_t hid[64 * HSTRIDE];
    __shared__ ushort_t h3t[LAST ? 64 * 68 : 1];
    int tid = threadIdx.x;
    int w = tid >> 6, lane = tid & 63, m = lane & 15, q = lane >> 4;
    for (int i = tid; i < 64 * 32; i += 256) {
        int r = i >> 5, c = HID2 + (i & 31);
        hid[r * HSTRIDE + c] = 0;
    }
    __syncthreads();

    int nb = blockIdx.x * 64 + w * 16;
    f32x4 acc1[7];
#pragma unroll
    for (int ct = 0; ct < 7; ct++) {
        int col = ct * 16 + m;
        float bv = (col < HID2) ? b1[col] : 0.f;
        acc1[ct] = (f32x4){bv, bv, bv, bv};
    }
    int anode = min(nb + m, n - 1);
#pragma unroll
    for (int ks = 0; ks < 2; ks++) {
        bf16x8 a = *(const bf16x8*)(zb + (size_t)anode * 64 + ks * 32 + q * 8);
#pragma unroll
        for (int ct = 0; ct < 7; ct++) {
            bf16x8 b = *(const bf16x8*)(w1f + ((size_t)(ct * 2 + ks) * 64 + lane) * 8);
            acc1[ct] = __builtin_amdgcn_mfma_f32_16x16x32_bf16(a, b, acc1[ct], 0, 0, 0);
        }
    }
#pragma unroll
    for (int ct = 0; ct < 7; ct++) {
#pragma unroll
        for (int r = 0; r < 4; r++) {
            float v = fmaxf(acc1[ct][r], 0.f);
            int row = w * 16 + q * 4 + r;
            hid[row * HSTRIDE + ct * 16 + m] = f2bf(v);
        }
    }
    f32x4 acc2[4];
#pragma unroll
    for (int ct = 0; ct < 4; ct++) {
        int col = ct * 16 + m;
        float bv = (col < HID) ? b2[col] : 0.f;
        acc2[ct] = (f32x4){bv, bv, bv, bv};
    }
#pragma unroll
    for (int ks = 0; ks < 4; ks++) {
        bf16x8 a = *(const bf16x8*)&hid[(w * 16 + m) * HSTRIDE + ks * 32 + q * 8];
#pragma unroll
        for (int ct = 0; ct < 4; ct++) {
            bf16x8 b = *(const bf16x8*)(w2f + ((size_t)(ct * 4 + ks) * 64 + lane) * 8);
            acc2[ct] = __builtin_amdgcn_mfma_f32_16x16x32_bf16(a, b, acc2[ct], 0, 0, 0);
        }
    }

    if (!LAST) {
#pragma unroll
        for (int ct = 0; ct < 4; ct++) {
#pragma unroll
            for (int r = 0; r < 4; r++) {
                int node = nb + q * 4 + r;
                if (node < n) {
                    float v = fmaxf(acc2[ct][r], 0.f);
                    hbout[(size_t)node * 64 + ct * 16 + m] = f2bf(v);
                }
            }
        }
    } else {
        // h3 (C-layout) -> LDS tile; wave-private rows, no barrier needed
#pragma unroll
        for (int ct = 0; ct < 4; ct++) {
#pragma unroll
            for (int r = 0; r < 4; r++) {
                float v = fmaxf(acc2[ct][r], 0.f);
                h3t[(w * 16 + q * 4 + r) * 68 + ct * 16 + m] = f2bf(v);
            }
        }
        // final: [16 x 256] @ [256 x 64]; segs x,h1,h2 from global, h3 from LDS
        f32x4 accF[4];
#pragma unroll
        for (int ct = 0; ct < 4; ct++) {
            int col = ct * 16 + m;
            float bv = (col < HID) ? lin_b[col] : 0.f;
            accF[ct] = (f32x4){bv, bv, bv, bv};
        }
        const ushort_t* segs[3] = {xb, h1b, h2b};
#pragma unroll
        for (int ks = 0; ks < 8; ks++) {
            bf16x8 a;
            if (ks < 6) {
                const ushort_t* p = segs[ks >> 1];
                a = *(const bf16x8*)(p + (size_t)anode * 64 + (ks & 1) * 32 + q * 8);
            } else {
                a = *(const bf16x8*)&h3t[(w * 16 + m) * 68 + (ks & 1) * 32 + q * 8];
            }
#pragma unroll
            for (int ct = 0; ct < 4; ct++) {
                bf16x8 b = *(const bf16x8*)(linf + ((size_t)(ct * 8 + ks) * 64 + lane) * 8);
                accF[ct] = __builtin_amdgcn_mfma_f32_16x16x32_bf16(a, b, accF[ct], 0, 0, 0);
            }
        }
#pragma unroll
        for (int ct = 0; ct < 4; ct++) {
            int col = ct * 16 + m;
            if (col < HID) {
#pragma unroll
                for (int r = 0; r < 4; r++) {
                    int node = nb + q * 4 + r;
                    if (node < n)
                        out[(size_t)node * HID + col] = accF[ct][r];
                }
            }
        }
    }
}

extern "C" void kernel_launch(void* const* d_in, const int* in_sizes, int n_in,
                              void* d_out, int out_size, void* d_ws, size_t ws_size,
                              hipStream_t stream) {
    const float* x     = (const float*)d_in[0];
    const int*   ei    = (const int*)d_in[1];
    const float* w1    = (const float*)d_in[2];
    const float* b1    = (const float*)d_in[3];
    const float* w2    = (const float*)d_in[4];
    const float* b2    = (const float*)d_in[5];
    const float* eps   = (const float*)d_in[6];
    const float* lin_w = (const float*)d_in[7];
    const float* lin_b = (const float*)d_in[8];
    float* out = (float*)d_out;

    const int N = in_sizes[0] / HID;       // 100000
    const int E = in_sizes[1] / 2;         // 3200000
    const int* src = ei;
    const int* dst = ei + E;

    const int NBIN = (N + 255) / 256;      // 391

    // ---- workspace layout (16B-aligned blocks); gather tables have extra zero row N ----
    char* p = (char*)d_ws;
    const size_t ROWS = (size_t)(N + 1) * 64 * 2;
    ushort_t* xb  = (ushort_t*)p;  p += ROWS;
    ushort_t* zb  = (ushort_t*)p;  p += ROWS;
    ushort_t* h1b = (ushort_t*)p;  p += ROWS;
    ushort_t* h2b = (ushort_t*)p;  p += ROWS;
    ushort_t* w1f = (ushort_t*)p;  p += 3 * 14 * 512 * 2;
    ushort_t* w2f = (ushort_t*)p;  p += 3 * 16 * 512 * 2;
    ushort_t* linf= (ushort_t*)p;  p += 32 * 512 * 2;
    int* ghist    = (int*)p;       p += 512 * 4;
    int* gcnt     = (int*)p;       p += 512 * 4;     // contiguous with ghist for one memset
    int* nrs      = (int*)p;       p += (size_t)(N + 4) * 4;
    int* ndeg     = (int*)p;       p += (size_t)(N + 4) * 4;
    uint_t* packed = (uint_t*)p;   p += (size_t)E * 4;
    int* srcsorted = (int*)p;      // E + NBIN*4096 + 64 entries (prefetch slack)

    ushort_t* hbs[3] = {xb, h1b, h2b};

    const int BLK = 256;
    const int NP1 = (E + P1_CHUNK - 1) / P1_CHUNK;   // 391
    const int NXBLK = (N * 16 + BLK - 1) / BLK;      // 6250
    const int NBUCK = (N + 63) / 64;                 // 1563
    dim3 blk(BLK);
    dim3 grid_agg(((size_t)N * 64 + BLK - 1) / BLK);

    // ---- setup (conv + bhist fused) then 2-pass radix CSR build ----
    hipMemsetAsync(ghist, 0, 1024 * sizeof(int), stream);   // ghist + gcnt
    setup_kernel<<<NXBLK + 32 + NP1, blk, 0, stream>>>(x, w1, w2, lin_w, dst,
                                                       xb, h1b, h2b,
                                                       w1f, w2f, linf, ghist, N, E, NXBLK);
    pass1_kernel<<<NP1, blk, 0, stream>>>(src, dst, ghist, gcnt, packed, E);
    pass2_kernel<<<NBIN, blk, 0, stream>>>(packed, ghist, srcsorted, nrs, ndeg, N);

    // ---- layers 1,2 ----
    for (int l = 0; l < 2; l++) {
        agg_kernel<<<grid_agg, blk, 0, stream>>>(hbs[l], nrs, ndeg, srcsorted, eps + l, zb, N);
        mlp_kernel<0><<<NBUCK, blk, 0, stream>>>(zb,
                                                 w1f + (size_t)l * 14 * 512,
                                                 b1 + (size_t)l * HID2,
                                                 w2f + (size_t)l * 16 * 512,
                                                 b2 + (size_t)l * HID,
                                                 hbs[l + 1],
                                                 nullptr, nullptr, nullptr,
                                                 nullptr, nullptr, nullptr, N);
    }
    // ---- layer 3 + fused final ----
    agg_kernel<<<grid_agg, blk, 0, stream>>>(h2b, nrs, ndeg, srcsorted, eps + 2, zb, N);
    mlp_kernel<1><<<NBUCK, blk, 0, stream>>>(zb,
                                             w1f + 2 * 14 * 512,
                                             b1 + 2 * HID2,
                                             w2f + 2 * 16 * 512,
                                             b2 + 2 * HID,
                                             nullptr,
                                             xb, h1b, h2b,
                                             linf, lin_b, out, N);
}